// Round 10
// baseline (4410.237 us; speedup 1.0000x reference)
//
#include <hip/hip_runtime.h>

#define H 256
#define SEQ 2048
#define NBATCH 64
#define M_TOTAL (NBATCH * SEQ)   // 131072 rows
#define BM 32                    // rows per block (32KB LDS)
#define GRID (M_TOTAL / BM)      // 4096

using bf16x8 = __attribute__((ext_vector_type(8))) short;
using u16x4  = __attribute__((ext_vector_type(4))) unsigned short;
using f32x4  = __attribute__((ext_vector_type(4))) float;

__device__ __forceinline__ unsigned short f2bf(float x) {
    union { float f; unsigned u; } v; v.f = x;
    unsigned r = v.u + 0x7fffu + ((v.u >> 16) & 1u);   // RNE
    return (unsigned short)(r >> 16);
}
__device__ __forceinline__ float bf2f(unsigned short b) {
    union { unsigned u; float f; } v; v.u = ((unsigned)b) << 16;
    return v.f;
}
__device__ __forceinline__ float asf(unsigned u) { union { unsigned u; float f; } v; v.u = u; return v.f; }
__device__ __forceinline__ unsigned asu(float f) { union { float f; unsigned u; } v; v.f = f; return v.u; }

__device__ __forceinline__ bf16x8 gload16(const void* p) {
    bf16x8 r;
    asm volatile("global_load_dwordx4 %0, %1, off" : "=v"(r) : "v"(p));
    return r;
}
// global -> LDS DMA, 16B per lane; LDS dest = wave-uniform base + lane*16
__device__ __forceinline__ void gload_lds16(const void* g, void* l) {
    __builtin_amdgcn_global_load_lds(
        (const __attribute__((address_space(1))) void*)g,
        (__attribute__((address_space(3))) void*)l, 16, 0, 0);
}
#define KEEP(x) asm volatile("" :: "v"(x))

// split two f32x4 into bf16 hi (truncation) + lo (residual)
__device__ __forceinline__ void split8v(const f32x4 a, const f32x4 b, bf16x8& hi, bf16x8& lo) {
#pragma unroll
    for (int j = 0; j < 4; ++j) {
        unsigned u = asu(a[j]);
        hi[j] = (short)(u >> 16);
        lo[j] = (short)(asu(a[j] - asf(u & 0xffff0000u)) >> 16);
    }
#pragma unroll
    for (int j = 0; j < 4; ++j) {
        unsigned u = asu(b[j]);
        hi[j + 4] = (short)(u >> 16);
        lo[j + 4] = (short)(asu(b[j] - asf(u & 0xffff0000u)) >> 16);
    }
}

// ---------------- prep 1: qpb[d] = sum_c q[c]*W2[c,d] + b1[d] + b2[d] ----------------
__global__ __launch_bounds__(256) void prep_qpb(const float* __restrict__ q,
                                                const float* __restrict__ W2,
                                                const float* __restrict__ b1,
                                                const float* __restrict__ b2,
                                                float* __restrict__ qpb) {
    int t = threadIdx.x;
    float s = 0.f;
#pragma unroll 8
    for (int c = 0; c < H; ++c) s = fmaf(q[c], W2[c * H + t], s);
    qpb[t] = s + b1[t] + b2[t];
}

// ---------------- prep 2: pack W1 into bf16 hi/lo MFMA fragment order --------------
__global__ __launch_bounds__(256) void prep_bpack(const float* __restrict__ W1,
                                                  unsigned short* __restrict__ Bpack) {
    int tid = blockIdx.x * 256 + threadIdx.x;  // 0..8191 = (ct,ks,lane)
    int ct = tid >> 9;
    int ks = (tid >> 6) & 7;
    int l  = tid & 63;
    bf16x8 hi, lo;
#pragma unroll
    for (int j = 0; j < 8; ++j) {
        int kk = ks * 32 + ((l >> 4) & 3) * 8 + j;
        int nn = ct * 16 + (l & 15);
        float w = W1[kk * H + nn];
        unsigned short h = f2bf(w);
        float rem = w - bf2f(h);
        hi[j] = (short)h;
        lo[j] = (short)f2bf(rem);
    }
    bf16x8* out = (bf16x8*)Bpack;
    out[((ct * 8 + ks) * 2 + 0) * 64 + l] = hi;
    out[((ct * 8 + ks) * 2 + 1) * 64 + l] = lo;
}

// ---------------- ablation-templated main ----------------
// MODE bits: 1=stage k->LDS (bf16 VALU path), 2=W1 load chain, 4=MFMA,
// 8=epilogue/store, 16=GLD staging (f32 via global_load_lds, swizzled source,
// read-side split; overrides bit0). REPS>1 = timing probe; rep parity XORs the
// tile index by 1 (keeps L3-warm regime, defeats cross-rep load CSE).
template <int MODE, int REPS>
__global__ __launch_bounds__(256, 5) void fused_tmpl(const float* __restrict__ kin,
                                                     const unsigned short* __restrict__ Bpack,
                                                     const float* __restrict__ qpb,
                                                     const float* __restrict__ Vp,
                                                     float* __restrict__ outp) {
    constexpr bool DO_GLD   = MODE & 16;
    constexpr bool DO_STAGE = (MODE & 1) && !DO_GLD;
    constexpr bool DO_W1    = MODE & 2;
    constexpr bool DO_MFMA  = MODE & 4;
    constexpr bool DO_EPI   = MODE & 8;

    __shared__ __align__(16) unsigned char lds[32768];
    unsigned char* Khi = lds;            // bf16 path: [32][256] hi
    unsigned char* Klo = lds + 16384;    // bf16 path: [32][256] lo
    // GLD path: lds = f32 [32][256], 16B-unit swizzle s = row*64 + (c16 ^ (row&7))

    const int t = threadIdx.x;           // 0..255

#pragma unroll 1
    for (int rep = 0; rep < REPS; ++rep) {
        const int m0 = (blockIdx.x ^ (rep & 1)) * BM;
        if (rep) __syncthreads();

        if constexpr (DO_GLD) {
            const int w64 = t & ~63;     // wave base (uniform within wave)
#pragma unroll
            for (int i = 0; i < 8; ++i) {
                int S    = i * 256 + t;              // 16B slot 0..2047
                int row  = S >> 6;
                int c16g = (S & 63) ^ (row & 7);     // pre-swizzled source
                const float* g = kin + (size_t)(m0 + row) * H + c16g * 4;
                void* l = (void*)(lds + (size_t)(i * 256 + w64) * 16);
                gload_lds16(g, l);
            }
            asm volatile("s_waitcnt vmcnt(0)");
        } else if constexpr (DO_STAGE) {
#pragma unroll
            for (int i = 0; i < 8; ++i) {
                int flat = i * 1024 + t * 4;      // covers [32][256] floats
                int r = flat >> 8;
                int c = flat & 255;
                const float4 v = *(const float4*)(kin + (size_t)(m0 + r) * H + c);
                unsigned ux = asu(v.x), uy = asu(v.y), uz = asu(v.z), uw = asu(v.w);
                u16x4 hi = {(unsigned short)(ux >> 16), (unsigned short)(uy >> 16),
                            (unsigned short)(uz >> 16), (unsigned short)(uw >> 16)};
                u16x4 lo = {(unsigned short)(asu(v.x - asf(ux & 0xffff0000u)) >> 16),
                            (unsigned short)(asu(v.y - asf(uy & 0xffff0000u)) >> 16),
                            (unsigned short)(asu(v.z - asf(uz & 0xffff0000u)) >> 16),
                            (unsigned short)(asu(v.w - asf(uw & 0xffff0000u)) >> 16)};
                int addr = (r * 512 + c * 2) ^ ((r & 7) << 4);
                *(u16x4*)(Khi + addr) = hi;
                *(u16x4*)(Klo + addr) = lo;
            }
        }
        __syncthreads();

        const int wave = t >> 6;             // 0..3 = n-group
        const int lane = t & 63;
        const int lhi  = lane >> 4;
        const int llo  = lane & 15;
        const int wn   = wave;

        f32x4 acc[4][2];
#pragma unroll
        for (int a = 0; a < 4; ++a)
#pragma unroll
            for (int b = 0; b < 2; ++b) acc[a][b] = (f32x4){0.f, 0.f, 0.f, 0.f};

        const char* bbase = (const char*)Bpack + (size_t)lane * 16;

        bf16x8 w1[2][4];
        bf16x8 kf[4];                        // [mt*2+h] current ks
        if constexpr (!DO_W1) {
#pragma unroll
            for (int s = 0; s < 2; ++s)
#pragma unroll
                for (int j = 0; j < 4; ++j) w1[s][j] = (bf16x8)(short)0;
        }

#define ISSUE_HALF(Hh, S)                                                          \
    do {                                                                           \
        const int ks_ = (Hh) >> 1, n0_ = ((Hh) & 1) * 2;                           \
        w1[S][0] = gload16(bbase + (((wn * 4 + n0_    ) * 8 + ks_) * 2 + 0) * 1024);\
        w1[S][1] = gload16(bbase + (((wn * 4 + n0_    ) * 8 + ks_) * 2 + 1) * 1024);\
        w1[S][2] = gload16(bbase + (((wn * 4 + n0_ + 1) * 8 + ks_) * 2 + 0) * 1024);\
        w1[S][3] = gload16(bbase + (((wn * 4 + n0_ + 1) * 8 + ks_) * 2 + 1) * 1024);\
    } while (0)

        if constexpr (DO_W1) ISSUE_HALF(0, 0);

#pragma unroll
        for (int Hh = 0; Hh < 16; ++Hh) {
            if ((Hh & 1) == 0) {
                const int ks = Hh >> 1;
                if constexpr (DO_GLD) {
#pragma unroll
                    for (int mt = 0; mt < 2; ++mt) {
                        int ml = mt * 16 + llo;
                        int cb = ks * 8 + lhi * 2;           // 16B-unit col
                        f32x4 fa = *(const f32x4*)(lds + (size_t)(ml * 64 + ((cb    ) ^ (ml & 7))) * 16);
                        f32x4 fb = *(const f32x4*)(lds + (size_t)(ml * 64 + ((cb + 1) ^ (ml & 7))) * 16);
                        split8v(fa, fb, kf[mt * 2 + 0], kf[mt * 2 + 1]);
                    }
                } else {
#pragma unroll
                    for (int mt = 0; mt < 2; ++mt) {
                        int ml = mt * 16 + llo;
                        int byte = (ml * 512 + ks * 64 + lhi * 16) ^ ((ml & 7) << 4);
                        kf[mt * 2 + 0] = *(const bf16x8*)(Khi + byte);
                        kf[mt * 2 + 1] = *(const bf16x8*)(Klo + byte);
                    }
                }
            }
            if constexpr (DO_W1) {
                if (Hh < 15) ISSUE_HALF(Hh + 1, (Hh + 1) & 1);
                if (Hh < 15) { asm volatile("s_waitcnt vmcnt(4)"); }
                else         { asm volatile("s_waitcnt vmcnt(0)"); }
                __builtin_amdgcn_sched_barrier(0);
            }
            const int slot = Hh & 1;
            if constexpr (DO_MFMA) {
#pragma unroll
                for (int p = 0; p < 3; ++p) {
                    const int ha = (p == 1) ? 1 : 0;
                    const int hb = (p == 2) ? 1 : 0;
#pragma unroll
                    for (int ntn = 0; ntn < 2; ++ntn) {
                        const int nt = (Hh & 1) * 2 + ntn;
#pragma unroll
                        for (int mt = 0; mt < 2; ++mt)
                            acc[nt][mt] = __builtin_amdgcn_mfma_f32_16x16x32_bf16(
                                w1[slot][ntn * 2 + ha], kf[mt * 2 + hb], acc[nt][mt], 0, 0, 0);
                    }
                }
            } else {
                KEEP(w1[slot][0]); KEEP(w1[slot][1]); KEEP(w1[slot][2]); KEEP(w1[slot][3]);
                KEEP(kf[0]); KEEP(kf[1]); KEEP(kf[2]); KEEP(kf[3]);
            }
        }
#undef ISSUE_HALF

        if constexpr (DO_EPI) {
            f32x4 qv[4], vv[4];
#pragma unroll
            for (int nt = 0; nt < 4; ++nt) {
                qv[nt] = *(const f32x4*)(qpb + wn * 64 + nt * 16 + lhi * 4);
                vv[nt] = *(const f32x4*)(Vp  + wn * 64 + nt * 16 + lhi * 4);
            }
            float sm[2] = {0.f, 0.f};
#pragma unroll
            for (int nt = 0; nt < 4; ++nt)
#pragma unroll
                for (int mt = 0; mt < 2; ++mt)
#pragma unroll
                    for (int i = 0; i < 4; ++i) {
                        float x = acc[nt][mt][i] + qv[nt][i];
                        float e = __expf(2.f * x);
                        float th = 1.f - 2.f * __builtin_amdgcn_rcpf(e + 1.f);
                        sm[mt] += th * vv[nt][i];
                    }
#pragma unroll
            for (int mt = 0; mt < 2; ++mt) {
                sm[mt] += __shfl_xor(sm[mt], 16, 64);
                sm[mt] += __shfl_xor(sm[mt], 32, 64);
            }
            __syncthreads();
            float* part = (float*)lds;       // [4 wn][32 m]
            if (lane < 16) {
                part[wn * 32 +  0 + lane] = sm[0];
                part[wn * 32 + 16 + lane] = sm[1];
            }
            __syncthreads();
            if (t < BM)
                outp[m0 + t] = part[t] + part[32 + t] + part[64 + t] + part[96 + t];
        } else {
#pragma unroll
            for (int a = 0; a < 4; ++a)
#pragma unroll
                for (int b = 0; b < 2; ++b) KEEP(acc[a][b]);
            if (t < BM) outp[m0 + t] = acc[0][0][0];   // token store, overwritten later
        }
    }
}

// ---------------- softmax over seq axis, in-place on d_out ----------------
__global__ __launch_bounds__(256) void softmax_kernel(float* __restrict__ out) {
    const int b = blockIdx.x;
    const int t = threadIdx.x;
    float* row = out + b * SEQ;
    float v[8];
#pragma unroll
    for (int j = 0; j < 8; ++j) v[j] = row[t + j * 256];
    float mx = v[0];
#pragma unroll
    for (int j = 1; j < 8; ++j) mx = fmaxf(mx, v[j]);
#pragma unroll
    for (int off = 1; off < 64; off <<= 1) mx = fmaxf(mx, __shfl_xor(mx, off, 64));
    __shared__ float redm[4], reds[4];
    int lane = t & 63, w = t >> 6;
    if (lane == 0) redm[w] = mx;
    __syncthreads();
    mx = fmaxf(fmaxf(redm[0], redm[1]), fmaxf(redm[2], redm[3]));
    float e[8], sum = 0.f;
#pragma unroll
    for (int j = 0; j < 8; ++j) { e[j] = __expf(v[j] - mx); sum += e[j]; }
#pragma unroll
    for (int off = 1; off < 64; off <<= 1) sum += __shfl_xor(sum, off, 64);
    if (lane == 0) reds[w] = sum;
    __syncthreads();
    float inv = 1.0f / (reds[0] + reds[1] + reds[2] + reds[3]);
#pragma unroll
    for (int j = 0; j < 8; ++j) row[t + j * 256] = e[j] * inv;
}

extern "C" void kernel_launch(void* const* d_in, const int* in_sizes, int n_in,
                              void* d_out, int out_size, void* d_ws, size_t ws_size,
                              hipStream_t stream) {
    const float* q  = (const float*)d_in[0];
    const float* k  = (const float*)d_in[1];
    const float* W1 = (const float*)d_in[2];
    const float* b1 = (const float*)d_in[3];
    const float* W2 = (const float*)d_in[4];
    const float* b2 = (const float*)d_in[5];
    const float* V  = (const float*)d_in[6];
    // d_in[7] = bv: softmax-invariant scalar, skipped.
    float* out = (float*)d_out;

    float* qpb = (float*)d_ws;                                     // 1 KB
    unsigned short* Bpack = (unsigned short*)((char*)d_ws + 1024); // 256 KB

    prep_qpb<<<1, 256, 0, stream>>>(q, W2, b1, b2, qpb);
    prep_bpack<<<32, 256, 0, stream>>>(W1, Bpack);

    // ---- x8 timing probes (top-5 rocprof rows = these, in this launch order) ----
    fused_tmpl<15, 8><<<GRID, 256, 0, stream>>>(k, Bpack, qpb, V, out);  // FULL
    fused_tmpl<14, 8><<<GRID, 256, 0, stream>>>(k, Bpack, qpb, V, out);  // no stage
    fused_tmpl<13, 8><<<GRID, 256, 0, stream>>>(k, Bpack, qpb, V, out);  // no W1
    fused_tmpl< 1, 8><<<GRID, 256, 0, stream>>>(k, Bpack, qpb, V, out);  // stage-only
    fused_tmpl<31, 8><<<GRID, 256, 0, stream>>>(k, Bpack, qpb, V, out);  // GLD-FULL

    // ---- real pipeline ----
    fused_tmpl<15, 1><<<GRID, 256, 0, stream>>>(k, Bpack, qpb, V, out);  // FULL
    softmax_kernel<<<NBATCH, 256, 0, stream>>>(out);
}

// Round 11
// 129.964 us; speedup vs baseline: 33.9342x; 33.9342x over previous
//
#include <hip/hip_runtime.h>

#define H 256
#define SEQ 2048
#define NBATCH 64
#define M_TOTAL (NBATCH * SEQ)   // 131072 rows
#define BM 32                    // rows per tile
#define TILES 4                  // tiles per block
#define GRID (M_TOTAL / BM / TILES)  // 1024

using bf16x8 = __attribute__((ext_vector_type(8))) short;
using u16x4  = __attribute__((ext_vector_type(4))) unsigned short;
using f32x4  = __attribute__((ext_vector_type(4))) float;

__device__ __forceinline__ unsigned short f2bf(float x) {
    union { float f; unsigned u; } v; v.f = x;
    unsigned r = v.u + 0x7fffu + ((v.u >> 16) & 1u);   // RNE
    return (unsigned short)(r >> 16);
}

// Raw 16B global loads pinned in registers (counted in our manual vmcnt scheme).
__device__ __forceinline__ bf16x8 gload16(const void* p) {
    bf16x8 r;
    asm volatile("global_load_dwordx4 %0, %1, off" : "=v"(r) : "v"(p));
    return r;
}
__device__ __forceinline__ f32x4 gloadf(const void* p) {
    f32x4 r;
    asm volatile("global_load_dwordx4 %0, %1, off" : "=v"(r) : "v"(p));
    return r;
}
#define SB0() __builtin_amdgcn_sched_barrier(0)

// ---------------- prep 1: qpb[d] = sum_c q[c]*W2[c,d] + b1[d] + b2[d] ----------------
__global__ __launch_bounds__(256) void prep_qpb(const float* __restrict__ q,
                                                const float* __restrict__ W2,
                                                const float* __restrict__ b1,
                                                const float* __restrict__ b2,
                                                float* __restrict__ qpb) {
    int t = threadIdx.x;
    float s = 0.f;
#pragma unroll 8
    for (int c = 0; c < H; ++c) s = fmaf(q[c], W2[c * H + t], s);
    qpb[t] = s + b1[t] + b2[t];
}

// ---------------- prep 2: pack W1 (RNE bf16, hi only) into MFMA fragment order -------
// granule(ct 0..15, ks 0..7)[lane]: elem j = W1bf[ks*32+(lane>>4)*8+j][ct*16+(lane&15)]
__global__ __launch_bounds__(256) void prep_bpack(const float* __restrict__ W1,
                                                  unsigned short* __restrict__ Bpack) {
    int tid = blockIdx.x * 256 + threadIdx.x;  // 0..8191 = (ct,ks,lane)
    int ct = tid >> 9;
    int ks = (tid >> 6) & 7;
    int l  = tid & 63;
    bf16x8 hi;
#pragma unroll
    for (int j = 0; j < 8; ++j) {
        int kk = ks * 32 + ((l >> 4) & 3) * 8 + j;
        int nn = ct * 16 + (l & 15);
        hi[j] = (short)f2bf(W1[kk * H + nn]);
    }
    ((bf16x8*)Bpack)[(ct * 8 + ks) * 64 + l] = hi;
}

// ---------------- main: scores[m] = sum_n tanh(k@W1 + qpb)[m,n] * V[n] ----------------
// Swapped GEMM C'[n,m] in single bf16 (RNE). 4 waves = 4 n-groups; wave owns
// 64n x 32m. W1 frags: depth-4 register ring from L2, counted vmcnt(6), refill
// after consume. k: 4 tiles/block; next tile's 8 loads issued after the last W1
// issue (T14), drained at next stage; split+ds_write between tiles. qpb/V in
// LDS so the epilogue issues no vmem. Raw s_barrier (no implicit vmcnt drain).
__global__ __launch_bounds__(256, 4) void fused_main(const float* __restrict__ kin,
                                                     const unsigned short* __restrict__ Bpack,
                                                     const float* __restrict__ qpb,
                                                     const float* __restrict__ Vp,
                                                     float* __restrict__ out_scores) {
    __shared__ __align__(16) unsigned char lds[18944];
    unsigned char* K    = lds;                       // [32][256] bf16, XOR-swizzled
    float*         part = (float*)(lds + 16384);     // [4 wn][32 m]
    unsigned char* qlds = lds + 16896;               // 256 f32
    unsigned char* vlds = lds + 17920;               // 256 f32

    const int t    = threadIdx.x;        // 0..255
    const int wave = t >> 6;             // 0..3 = n-group
    const int lane = t & 63;
    const int lhi  = lane >> 4;          // 0..3
    const int llo  = lane & 15;          // 0..15
    const int wn   = wave;

    // qpb/V -> LDS (visibility via tile0's stage barrier)
    if (t < 64)       *(f32x4*)(qlds + t * 16)        = *(const f32x4*)(qpb + t * 4);
    else if (t < 128) *(f32x4*)(vlds + (t - 64) * 16) = *(const f32x4*)(Vp + (t - 64) * 4);

    // XCD-aware block swizzle (1024 % 8 == 0 -> bijective)
    const int bid  = blockIdx.x;
    const int swz  = (bid & 7) * (GRID / 8) + (bid >> 3);
    const int base = swz * (BM * TILES);

    const int rr = t >> 6;               // staging row-within-group
    const int cc = (t & 63) * 4;         // staging col

    // ---- prefetch tile 0 into registers ----
    f32x4 pf[8];
#pragma unroll
    for (int i = 0; i < 8; ++i)
        pf[i] = gloadf(kin + (size_t)(base + i * 4 + rr) * H + cc);

    const char* bb = (const char*)Bpack + (size_t)lane * 16;

#define ISSUE_HALF(Hh, S)                                                      \
    do {                                                                       \
        const int ks_ = (Hh) >> 1, n0_ = ((Hh) & 1) * 2;                       \
        w1r[S][0] = gload16(bb + (size_t)((wn * 4 + n0_    ) * 8 + ks_) * 1024);\
        w1r[S][1] = gload16(bb + (size_t)((wn * 4 + n0_ + 1) * 8 + ks_) * 1024);\
    } while (0)

#pragma unroll 1
    for (int j = 0; j < TILES; ++j) {
        const int m0 = base + j * BM;

        // ---- STAGE tile j from pf regs ----
        asm volatile("s_waitcnt vmcnt(0)" ::: "memory");   // pf landed
        SB0();

        bf16x8 w1r[4][2];                 // depth-4 W1 ring (issued below)
        ISSUE_HALF(0, 0);
        ISSUE_HALF(1, 1);
        ISSUE_HALF(2, 2);
        ISSUE_HALF(3, 3);                 // L2 latency overlaps the split below

#pragma unroll
        for (int i = 0; i < 8; ++i) {
            int r = i * 4 + rr;
            u16x4 hv = {f2bf(pf[i][0]), f2bf(pf[i][1]), f2bf(pf[i][2]), f2bf(pf[i][3])};
            int addr = (r * 512 + cc * 2) ^ ((r & 7) << 4);
            *(u16x4*)(K + addr) = hv;
        }
        asm volatile("s_waitcnt lgkmcnt(0)" ::: "memory");
        __builtin_amdgcn_s_barrier();
        SB0();

        // ---- COMPUTE tile j ----
        f32x4 acc[4][2];
#pragma unroll
        for (int a = 0; a < 4; ++a)
#pragma unroll
            for (int b = 0; b < 2; ++b) acc[a][b] = (f32x4){0.f, 0.f, 0.f, 0.f};

        bf16x8 kf[2];
#pragma unroll
        for (int Hh = 0; Hh < 16; ++Hh) {
            if ((Hh & 1) == 0) {
                const int ks = Hh >> 1;
#pragma unroll
                for (int mt = 0; mt < 2; ++mt) {
                    int ml = mt * 16 + llo;
                    int byte = (ml * 512 + ks * 64 + lhi * 16) ^ ((ml & 7) << 4);
                    kf[mt] = *(const bf16x8*)(K + byte);
                }
            }
            // wait for half Hh only; halves Hh+1..Hh+3 (and pf at Hh==15) in flight
            if (Hh <= 12)      { asm volatile("s_waitcnt vmcnt(6)"); }
            else if (Hh == 13) { asm volatile("s_waitcnt vmcnt(4)"); }
            else if (Hh == 14) { asm volatile("s_waitcnt vmcnt(2)"); }
            else {
                if (j < TILES - 1) { asm volatile("s_waitcnt vmcnt(8)"); }
                else               { asm volatile("s_waitcnt vmcnt(0)"); }
            }
            SB0();

            const int slot = Hh & 3;
            const int nt0  = (Hh & 1) * 2;
            acc[nt0    ][0] = __builtin_amdgcn_mfma_f32_16x16x32_bf16(w1r[slot][0], kf[0], acc[nt0    ][0], 0, 0, 0);
            acc[nt0    ][1] = __builtin_amdgcn_mfma_f32_16x16x32_bf16(w1r[slot][0], kf[1], acc[nt0    ][1], 0, 0, 0);
            acc[nt0 + 1][0] = __builtin_amdgcn_mfma_f32_16x16x32_bf16(w1r[slot][1], kf[0], acc[nt0 + 1][0], 0, 0, 0);
            acc[nt0 + 1][1] = __builtin_amdgcn_mfma_f32_16x16x32_bf16(w1r[slot][1], kf[1], acc[nt0 + 1][1], 0, 0, 0);

            if (Hh < 12) ISSUE_HALF(Hh + 4, Hh & 3);       // refill after consume
            if (Hh == 14 && j < TILES - 1) {               // T14: prefetch tile j+1
#pragma unroll
                for (int i = 0; i < 8; ++i)
                    pf[i] = gloadf(kin + (size_t)(m0 + BM + i * 4 + rr) * H + cc);
            }
        }

        // ---- EPILOGUE tile j (no vmem except the final store) ----
        float sm0 = 0.f, sm1 = 0.f;
#pragma unroll
        for (int nt = 0; nt < 4; ++nt) {
            const int off = (wn * 64 + nt * 16 + lhi * 4) * 4;
            f32x4 qv = *(const f32x4*)(qlds + off);
            f32x4 vv = *(const f32x4*)(vlds + off);
#pragma unroll
            for (int i = 0; i < 4; ++i) {
                float x0 = acc[nt][0][i] + qv[i];
                float e0 = __expf(2.f * x0);
                sm0 += (1.f - 2.f * __builtin_amdgcn_rcpf(e0 + 1.f)) * vv[i];
                float x1 = acc[nt][1][i] + qv[i];
                float e1 = __expf(2.f * x1);
                sm1 += (1.f - 2.f * __builtin_amdgcn_rcpf(e1 + 1.f)) * vv[i];
            }
        }
        sm0 += __shfl_xor(sm0, 16, 64); sm0 += __shfl_xor(sm0, 32, 64);
        sm1 += __shfl_xor(sm1, 16, 64); sm1 += __shfl_xor(sm1, 32, 64);

        if (lane < 16) {
            part[wn * 32 +  0 + lane] = sm0;
            part[wn * 32 + 16 + lane] = sm1;
        }
        asm volatile("s_waitcnt lgkmcnt(0)" ::: "memory");
        __builtin_amdgcn_s_barrier();       // all waves done computing tile j
        SB0();
        if (t < BM)
            out_scores[m0 + t] = part[t] + part[32 + t] + part[64 + t] + part[96 + t];
        // next stage's writes go to K (disjoint from part); next part write is
        // behind the next stage barrier -> no trailing barrier needed
    }
#undef ISSUE_HALF
}

// ---------------- softmax over seq axis, in-place on d_out ----------------
__global__ __launch_bounds__(256) void softmax_kernel(float* __restrict__ out) {
    const int b = blockIdx.x;
    const int t = threadIdx.x;
    float* row = out + b * SEQ;
    float v[8];
#pragma unroll
    for (int j = 0; j < 8; ++j) v[j] = row[t + j * 256];
    float mx = v[0];
#pragma unroll
    for (int j = 1; j < 8; ++j) mx = fmaxf(mx, v[j]);
#pragma unroll
    for (int off = 1; off < 64; off <<= 1) mx = fmaxf(mx, __shfl_xor(mx, off, 64));
    __shared__ float redm[4], reds[4];
    int lane = t & 63, w = t >> 6;
    if (lane == 0) redm[w] = mx;
    __syncthreads();
    mx = fmaxf(fmaxf(redm[0], redm[1]), fmaxf(redm[2], redm[3]));
    float e[8], sum = 0.f;
#pragma unroll
    for (int j = 0; j < 8; ++j) { e[j] = __expf(v[j] - mx); sum += e[j]; }
#pragma unroll
    for (int off = 1; off < 64; off <<= 1) sum += __shfl_xor(sum, off, 64);
    if (lane == 0) reds[w] = sum;
    __syncthreads();
    float inv = 1.0f / (reds[0] + reds[1] + reds[2] + reds[3]);
#pragma unroll
    for (int j = 0; j < 8; ++j) row[t + j * 256] = e[j] * inv;
}

extern "C" void kernel_launch(void* const* d_in, const int* in_sizes, int n_in,
                              void* d_out, int out_size, void* d_ws, size_t ws_size,
                              hipStream_t stream) {
    const float* q  = (const float*)d_in[0];
    const float* k  = (const float*)d_in[1];
    const float* W1 = (const float*)d_in[2];
    const float* b1 = (const float*)d_in[3];
    const float* W2 = (const float*)d_in[4];
    const float* b2 = (const float*)d_in[5];
    const float* V  = (const float*)d_in[6];
    // d_in[7] = bv: softmax-invariant scalar, skipped.
    float* out = (float*)d_out;

    float* qpb = (float*)d_ws;                                     // 1 KB
    unsigned short* Bpack = (unsigned short*)((char*)d_ws + 1024); // 128 KB

    prep_qpb<<<1, 256, 0, stream>>>(q, W2, b1, b2, qpb);
    prep_bpack<<<32, 256, 0, stream>>>(W1, Bpack);
    fused_main<<<GRID, 256, 0, stream>>>(k, Bpack, qpb, V, out);
    softmax_kernel<<<NBATCH, 256, 0, stream>>>(out);
}

// Round 12
// 58.257 us; speedup vs baseline: 75.7029x; 2.2309x over previous
//
#include <hip/hip_runtime.h>

#define H 256
#define SEQ 2048
#define NBATCH 64
#define M_TOTAL (NBATCH * SEQ)   // 131072 rows
#define BM 32                    // rows per tile
#define TILES 4                  // tiles per block
#define GRID (M_TOTAL / BM / TILES)  // 1024

using bf16x8 = __attribute__((ext_vector_type(8))) short;
using f32x4  = __attribute__((ext_vector_type(4))) float;

__device__ __forceinline__ unsigned short f2bf(float x) {
    union { float f; unsigned u; } v; v.f = x;
    unsigned r = v.u + 0x7fffu + ((v.u >> 16) & 1u);   // RNE
    return (unsigned short)(r >> 16);
}

__device__ __forceinline__ bf16x8 gload16(const void* p) {
    bf16x8 r;
    asm volatile("global_load_dwordx4 %0, %1, off" : "=v"(r) : "v"(p));
    return r;
}
__device__ __forceinline__ f32x4 gloadf(const void* p) {
    f32x4 r;
    asm volatile("global_load_dwordx4 %0, %1, off" : "=v"(r) : "v"(p));
    return r;
}
__device__ __forceinline__ void gstore(void* p, float v) {
    asm volatile("global_store_dword %0, %1, off" :: "v"(p), "v"(v) : "memory");
}
__device__ __forceinline__ void gload_lds16(const void* g, void* l) {
    __builtin_amdgcn_global_load_lds(
        (const __attribute__((address_space(1))) void*)g,
        (__attribute__((address_space(3))) void*)l, 16, 0, 0);
}
#define SB0() __builtin_amdgcn_sched_barrier(0)
__device__ __forceinline__ void waitvm(int n) {   // literal-only s_waitcnt
    switch (n) {
    case  0: asm volatile("s_waitcnt vmcnt(0)");  break;
    case  2: asm volatile("s_waitcnt vmcnt(2)");  break;
    case  4: asm volatile("s_waitcnt vmcnt(4)");  break;
    case  6: asm volatile("s_waitcnt vmcnt(6)");  break;
    case  8: asm volatile("s_waitcnt vmcnt(8)");  break;
    case 10: asm volatile("s_waitcnt vmcnt(10)"); break;
    case 12: asm volatile("s_waitcnt vmcnt(12)"); break;
    default: asm volatile("s_waitcnt vmcnt(14)"); break;
    }
}

// ---------------- prep 1: qpb[d] = sum_c q[c]*W2[c,d] + b1[d] + b2[d] ----------------
__global__ __launch_bounds__(256) void prep_qpb(const float* __restrict__ q,
                                                const float* __restrict__ W2,
                                                const float* __restrict__ b1,
                                                const float* __restrict__ b2,
                                                float* __restrict__ qpb) {
    int t = threadIdx.x;
    float s = 0.f;
#pragma unroll 8
    for (int c = 0; c < H; ++c) s = fmaf(q[c], W2[c * H + t], s);
    qpb[t] = s + b1[t] + b2[t];
}

// ---------------- prep 2: pack W1 (RNE bf16) into MFMA fragment order ----------------
// granule(ct 0..15, ks 0..7)[lane]: elem j = W1bf[ks*32+(lane>>4)*8+j][ct*16+(lane&15)]
__global__ __launch_bounds__(256) void prep_bpack(const float* __restrict__ W1,
                                                  unsigned short* __restrict__ Bpack) {
    int tid = blockIdx.x * 256 + threadIdx.x;  // (ct,ks,lane)
    int ct = tid >> 9;
    int ks = (tid >> 6) & 7;
    int l  = tid & 63;
    bf16x8 hi;
#pragma unroll
    for (int j = 0; j < 8; ++j) {
        int kk = ks * 32 + ((l >> 4) & 3) * 8 + j;
        int nn = ct * 16 + (l & 15);
        hi[j] = (short)f2bf(W1[kk * H + nn]);
    }
    ((bf16x8*)Bpack)[(ct * 8 + ks) * 64 + l] = hi;
}

// ---------------- main ----------------
// k: f32 in LDS via global_load_lds, double-buffered; next tile's GLDs issued at
// phase 11, drained only at the swap barrier (counted vmcnt, never 0 mid-stream).
// W1: depth-4 register ring, vmcnt(6) steady. Single-bf16 (validated R11).
// LDS layout: 16B-slot swizzle phys = c ^ (row&7); GLD writes linear lane-slots
// with pre-swizzled GLOBAL source; reads apply the same XOR (rule #21).
__global__ __launch_bounds__(256) void fused_main(const float* __restrict__ kin,
                                                  const unsigned short* __restrict__ Bpack,
                                                  const float* __restrict__ qpb,
                                                  const float* __restrict__ Vp,
                                                  float* __restrict__ out_scores) {
    __shared__ __align__(16) unsigned char Kbuf[2][32768];   // exactly 64 KB

    const int t    = threadIdx.x;        // 0..255
    const int wave = t >> 6;             // 0..3 = n-group
    const int lane = t & 63;
    const int lhi  = lane >> 4;
    const int llo  = lane & 15;
    const int wn   = wave;
    const int base = blockIdx.x * (BM * TILES);

    // qpb/V -> registers via asm loads (kept out of compiler vmcnt tracking)
    f32x4 qv[4], vv[4];
#pragma unroll
    for (int nt = 0; nt < 4; ++nt) {
        qv[nt] = gloadf(qpb + wn * 64 + nt * 16 + lhi * 4);
        vv[nt] = gloadf(Vp  + wn * 64 + nt * 16 + lhi * 4);
    }
    waitvm(0); SB0();

    // ---- stage tile 0 -> buf 0 (8 GLD issues per wave) ----
#pragma unroll
    for (int i = 0; i < 8; ++i) {
        int r = i * 4 + wave;
        const float* g = kin + (size_t)(base + r) * H + ((lane ^ (r & 7)) << 2);
        gload_lds16(g, &Kbuf[0][r * 1024]);
    }

    const char* bb = (const char*)Bpack + (size_t)lane * 16;
    bf16x8 w1r[4][2];
#define ISSUE_HALF(Hh, S)                                                       \
    do {                                                                        \
        const int ks_ = (Hh) >> 1, n0_ = ((Hh) & 1) * 2;                        \
        w1r[S][0] = gload16(bb + (size_t)((wn * 4 + n0_    ) * 8 + ks_) * 1024);\
        w1r[S][1] = gload16(bb + (size_t)((wn * 4 + n0_ + 1) * 8 + ks_) * 1024);\
    } while (0)

    ISSUE_HALF(0, 0); ISSUE_HALF(1, 1); ISSUE_HALF(2, 2); ISSUE_HALF(3, 3);
    waitvm(8); SB0();                      // GLD retired, ring (8) in flight
    __builtin_amdgcn_s_barrier();          // buf 0 visible

#pragma unroll 1
    for (int j = 0; j < TILES; ++j) {
        const int m0 = base + j * BM;
        const unsigned char* Kb = &Kbuf[j & 1][0];

        f32x4 acc[4][2];
#pragma unroll
        for (int a = 0; a < 4; ++a)
#pragma unroll
            for (int b = 0; b < 2; ++b) acc[a][b] = (f32x4){0.f, 0.f, 0.f, 0.f};

        bf16x8 kf[2];
#pragma unroll
        for (int Hh = 0; Hh < 16; ++Hh) {
            if ((Hh & 1) == 0) {
                const int ks = Hh >> 1;
                const int s0 = ks * 8 + lhi * 2;
                const int x  = llo & 7;
                f32x4 fa0 = *(const f32x4*)(Kb + (llo       ) * 1024 + ((s0    ) ^ x) * 16);
                f32x4 fb0 = *(const f32x4*)(Kb + (llo       ) * 1024 + ((s0 + 1) ^ x) * 16);
                f32x4 fa1 = *(const f32x4*)(Kb + (16 + llo  ) * 1024 + ((s0    ) ^ x) * 16);
                f32x4 fb1 = *(const f32x4*)(Kb + (16 + llo  ) * 1024 + ((s0 + 1) ^ x) * 16);
                union KU { unsigned u[4]; bf16x8 v; } k0, k1;
                asm("v_cvt_pk_bf16_f32 %0, %1, %2" : "=v"(k0.u[0]) : "v"(fa0[0]), "v"(fa0[1]));
                asm("v_cvt_pk_bf16_f32 %0, %1, %2" : "=v"(k0.u[1]) : "v"(fa0[2]), "v"(fa0[3]));
                asm("v_cvt_pk_bf16_f32 %0, %1, %2" : "=v"(k0.u[2]) : "v"(fb0[0]), "v"(fb0[1]));
                asm("v_cvt_pk_bf16_f32 %0, %1, %2" : "=v"(k0.u[3]) : "v"(fb0[2]), "v"(fb0[3]));
                asm("v_cvt_pk_bf16_f32 %0, %1, %2" : "=v"(k1.u[0]) : "v"(fa1[0]), "v"(fa1[1]));
                asm("v_cvt_pk_bf16_f32 %0, %1, %2" : "=v"(k1.u[1]) : "v"(fa1[2]), "v"(fa1[3]));
                asm("v_cvt_pk_bf16_f32 %0, %1, %2" : "=v"(k1.u[2]) : "v"(fb1[0]), "v"(fb1[1]));
                asm("v_cvt_pk_bf16_f32 %0, %1, %2" : "=v"(k1.u[3]) : "v"(fb1[2]), "v"(fb1[3]));
                kf[0] = k0.v; kf[1] = k1.v;
            }
            // counted waits: ring half Hh ready; GLD (8) stays in flight Hh>=12
            if (Hh <= 11)            waitvm(6);
            else if (j < TILES - 1)  waitvm(8 + (15 - Hh) * 2);   // 14,12,10,8
            else                     waitvm((15 - Hh) * 2);       // 6,4,2,0
            SB0();

            {
                const int slot = Hh & 3;
                const int nt0  = (Hh & 1) * 2;
                acc[nt0    ][0] = __builtin_amdgcn_mfma_f32_16x16x32_bf16(w1r[slot][0], kf[0], acc[nt0    ][0], 0, 0, 0);
                acc[nt0    ][1] = __builtin_amdgcn_mfma_f32_16x16x32_bf16(w1r[slot][0], kf[1], acc[nt0    ][1], 0, 0, 0);
                acc[nt0 + 1][0] = __builtin_amdgcn_mfma_f32_16x16x32_bf16(w1r[slot][1], kf[0], acc[nt0 + 1][0], 0, 0, 0);
                acc[nt0 + 1][1] = __builtin_amdgcn_mfma_f32_16x16x32_bf16(w1r[slot][1], kf[1], acc[nt0 + 1][1], 0, 0, 0);
            }
            if (Hh < 12) ISSUE_HALF(Hh + 4, Hh & 3);          // refill consumed slot
            if (Hh == 11 && j < TILES - 1) {                  // stage tile j+1
                unsigned char* nb = &Kbuf[(j + 1) & 1][0];
#pragma unroll
                for (int i = 0; i < 8; ++i) {
                    int r = i * 4 + wave;
                    const float* g = kin + (size_t)(m0 + BM + r) * H + ((lane ^ (r & 7)) << 2);
                    gload_lds16(g, nb + r * 1024);
                }
            }
        }

        // ---- epilogue ----
        __builtin_amdgcn_s_barrier();            // all waves done reading Kb
        float* part = (float*)(&Kbuf[j & 1][0]); // dead buffer reused
        float sm0 = 0.f, sm1 = 0.f;
#pragma unroll
        for (int nt = 0; nt < 4; ++nt)
#pragma unroll
            for (int i = 0; i < 4; ++i) {
                float x0 = acc[nt][0][i] + qv[nt][i];
                float e0 = __expf(2.f * x0);
                sm0 += (1.f - 2.f * __builtin_amdgcn_rcpf(e0 + 1.f)) * vv[nt][i];
                float x1 = acc[nt][1][i] + qv[nt][i];
                float e1 = __expf(2.f * x1);
                sm1 += (1.f - 2.f * __builtin_amdgcn_rcpf(e1 + 1.f)) * vv[nt][i];
            }
        sm0 += __shfl_xor(sm0, 16, 64); sm0 += __shfl_xor(sm0, 32, 64);
        sm1 += __shfl_xor(sm1, 16, 64); sm1 += __shfl_xor(sm1, 32, 64);
        if (lane < 16) {
            part[wn * 32 +  0 + lane] = sm0;
            part[wn * 32 + 16 + lane] = sm1;
        }
        asm volatile("s_waitcnt lgkmcnt(0)" ::: "memory");
        __builtin_amdgcn_s_barrier();
        SB0();
        if (t < BM) {
            float r = part[t] + part[32 + t] + part[64 + t] + part[96 + t];
            gstore(out_scores + m0 + t, r);
        }
        if (j < TILES - 1) {
            ISSUE_HALF(0, 0); ISSUE_HALF(1, 1); ISSUE_HALF(2, 2); ISSUE_HALF(3, 3);
            waitvm(8); SB0();                    // GLD+store retired, ring kept
            __builtin_amdgcn_s_barrier();        // buf j+1 visible
        }
    }
#undef ISSUE_HALF
}

// ---------------- softmax over seq axis, in-place on d_out ----------------
__global__ __launch_bounds__(256) void softmax_kernel(float* __restrict__ out) {
    const int b = blockIdx.x;
    const int t = threadIdx.x;
    float* row = out + b * SEQ;
    float v[8];
#pragma unroll
    for (int j = 0; j < 8; ++j) v[j] = row[t + j * 256];
    float mx = v[0];
#pragma unroll
    for (int j = 1; j < 8; ++j) mx = fmaxf(mx, v[j]);
#pragma unroll
    for (int off = 1; off < 64; off <<= 1) mx = fmaxf(mx, __shfl_xor(mx, off, 64));
    __shared__ float redm[4], reds[4];
    int lane = t & 63, w = t >> 6;
    if (lane == 0) redm[w] = mx;
    __syncthreads();
    mx = fmaxf(fmaxf(redm[0], redm[1]), fmaxf(redm[2], redm[3]));
    float e[8], sum = 0.f;
#pragma unroll
    for (int j = 0; j < 8; ++j) { e[j] = __expf(v[j] - mx); sum += e[j]; }
#pragma unroll
    for (int off = 1; off < 64; off <<= 1) sum += __shfl_xor(sum, off, 64);
    if (lane == 0) reds[w] = sum;
    __syncthreads();
    float inv = 1.0f / (reds[0] + reds[1] + reds[2] + reds[3]);
#pragma unroll
    for (int j = 0; j < 8; ++j) row[t + j * 256] = e[j] * inv;
}

extern "C" void kernel_launch(void* const* d_in, const int* in_sizes, int n_in,
                              void* d_out, int out_size, void* d_ws, size_t ws_size,
                              hipStream_t stream) {
    const float* q  = (const float*)d_in[0];
    const float* k  = (const float*)d_in[1];
    const float* W1 = (const float*)d_in[2];
    const float* b1 = (const float*)d_in[3];
    const float* W2 = (const float*)d_in[4];
    const float* b2 = (const float*)d_in[5];
    const float* V  = (const float*)d_in[6];
    // d_in[7] = bv: softmax-invariant scalar, skipped.
    float* out = (float*)d_out;

    float* qpb = (float*)d_ws;                                     // 1 KB
    unsigned short* Bpack = (unsigned short*)((char*)d_ws + 1024); // 128 KB

    prep_qpb<<<1, 256, 0, stream>>>(q, W2, b1, b2, qpb);
    prep_bpack<<<32, 256, 0, stream>>>(W1, Bpack);
    fused_main<<<GRID, 256, 0, stream>>>(k, Bpack, qpb, V, out);
    softmax_kernel<<<NBATCH, 256, 0, stream>>>(out);
}

// Round 13
// 57.519 us; speedup vs baseline: 76.6747x; 1.0128x over previous
//
#include <hip/hip_runtime.h>

#define H 256
#define SEQ 2048
#define NBATCH 64
#define M_TOTAL (NBATCH * SEQ)   // 131072 rows
#define BM 32                    // rows per tile
#define TILES 4                  // tiles per block
#define GRID (M_TOTAL / BM / TILES)  // 1024

using bf16x8 = __attribute__((ext_vector_type(8))) short;
using f32x4  = __attribute__((ext_vector_type(4))) float;

__device__ __forceinline__ unsigned short f2bf(float x) {
    union { float f; unsigned u; } v; v.f = x;
    unsigned r = v.u + 0x7fffu + ((v.u >> 16) & 1u);   // RNE
    return (unsigned short)(r >> 16);
}

__device__ __forceinline__ bf16x8 gload16(const void* p) {
    bf16x8 r;
    asm volatile("global_load_dwordx4 %0, %1, off" : "=v"(r) : "v"(p));
    return r;
}
__device__ __forceinline__ f32x4 gloadf(const void* p) {
    f32x4 r;
    asm volatile("global_load_dwordx4 %0, %1, off" : "=v"(r) : "v"(p));
    return r;
}
__device__ __forceinline__ void gstore(void* p, float v) {
    asm volatile("global_store_dword %0, %1, off" :: "v"(p), "v"(v) : "memory");
}
__device__ __forceinline__ void gload_lds16(const void* g, void* l) {
    __builtin_amdgcn_global_load_lds(
        (const __attribute__((address_space(1))) void*)g,
        (__attribute__((address_space(3))) void*)l, 16, 0, 0);
}
#define SB0() __builtin_amdgcn_sched_barrier(0)
__device__ __forceinline__ void waitvm(int n) {   // literal-only s_waitcnt
    switch (n) {
    case  0: asm volatile("s_waitcnt vmcnt(0)");  break;
    case  2: asm volatile("s_waitcnt vmcnt(2)");  break;
    case  4: asm volatile("s_waitcnt vmcnt(4)");  break;
    case  6: asm volatile("s_waitcnt vmcnt(6)");  break;
    case  8: asm volatile("s_waitcnt vmcnt(8)");  break;
    case 10: asm volatile("s_waitcnt vmcnt(10)"); break;
    case 12: asm volatile("s_waitcnt vmcnt(12)"); break;
    default: asm volatile("s_waitcnt vmcnt(14)"); break;
    }
}

// ------- prep 1a: partial[g][d] = sum_{c in g-slice} q[c]*W2[c,d]  (16 blocks) -------
__global__ __launch_bounds__(256) void prep_qpb1(const float* __restrict__ q,
                                                 const float* __restrict__ W2,
                                                 float* __restrict__ partial) {
    const int g = blockIdx.x;      // 0..15
    const int t = threadIdx.x;     // d
    float s = 0.f;
#pragma unroll
    for (int i = 0; i < 16; ++i) {
        int c = g * 16 + i;
        s = fmaf(q[c], W2[c * H + t], s);
    }
    partial[g * H + t] = s;
}

// ------- prep 1b+2 combined: blocks 0..31 pack W1; block 32 reduces qpb -------------
// W1 pack granule(ct 0..15, ks 0..7)[lane]: elem j = W1bf[ks*32+(lane>>4)*8+j][ct*16+(lane&15)]
__global__ __launch_bounds__(256) void prep_misc(const float* __restrict__ W1,
                                                 unsigned short* __restrict__ Bpack,
                                                 const float* __restrict__ partial,
                                                 const float* __restrict__ b1,
                                                 const float* __restrict__ b2,
                                                 float* __restrict__ qpb) {
    if (blockIdx.x < 32) {
        int tid = blockIdx.x * 256 + threadIdx.x;  // (ct,ks,lane)
        int ct = tid >> 9;
        int ks = (tid >> 6) & 7;
        int l  = tid & 63;
        bf16x8 hi;
#pragma unroll
        for (int j = 0; j < 8; ++j) {
            int kk = ks * 32 + ((l >> 4) & 3) * 8 + j;
            int nn = ct * 16 + (l & 15);
            hi[j] = (short)f2bf(W1[kk * H + nn]);
        }
        ((bf16x8*)Bpack)[(ct * 8 + ks) * 64 + l] = hi;
    } else {
        const int t = threadIdx.x;
        float s = b1[t] + b2[t];
#pragma unroll
        for (int g = 0; g < 16; ++g) s += partial[g * H + t];
        qpb[t] = s;
    }
}

// ---------------- main ----------------
// k: f32 in LDS via global_load_lds, double-buffered; next tile's GLDs issued at
// phase 11, drained only at the swap barrier (counted vmcnt, never 0 mid-stream).
// W1: depth-4 register ring, vmcnt(6) steady. Single-bf16 (validated R11/R12).
// kf: pair-prefetched — raw f32 LDS loads for pair p+1 issued at pair-p start,
// cvt_pk'd at pair-p end => ds_read latency spans 2 phases (hidden).
// LDS 16B-slot swizzle phys = c ^ (row&7); GLD linear dest + pre-swizzled source.
__global__ __launch_bounds__(256) void fused_main(const float* __restrict__ kin,
                                                  const unsigned short* __restrict__ Bpack,
                                                  const float* __restrict__ qpb,
                                                  const float* __restrict__ Vp,
                                                  float* __restrict__ out_scores) {
    __shared__ __align__(16) unsigned char Kbuf[2][32768];   // exactly 64 KB

    const int t    = threadIdx.x;        // 0..255
    const int wave = t >> 6;             // 0..3 = n-group
    const int lane = t & 63;
    const int lhi  = lane >> 4;
    const int llo  = lane & 15;
    const int wn   = wave;
    const int base = blockIdx.x * (BM * TILES);

    // qpb/V -> registers via asm loads (kept out of compiler vmcnt tracking)
    f32x4 qv[4], vv[4];
#pragma unroll
    for (int nt = 0; nt < 4; ++nt) {
        qv[nt] = gloadf(qpb + wn * 64 + nt * 16 + lhi * 4);
        vv[nt] = gloadf(Vp  + wn * 64 + nt * 16 + lhi * 4);
    }
    waitvm(0); SB0();

    // ---- stage tile 0 -> buf 0 (8 GLD issues per wave) ----
#pragma unroll
    for (int i = 0; i < 8; ++i) {
        int r = i * 4 + wave;
        const float* g = kin + (size_t)(base + r) * H + ((lane ^ (r & 7)) << 2);
        gload_lds16(g, &Kbuf[0][r * 1024]);
    }

    const char* bb = (const char*)Bpack + (size_t)lane * 16;
    bf16x8 w1r[4][2];
#define ISSUE_HALF(Hh, S)                                                       \
    do {                                                                        \
        const int ks_ = (Hh) >> 1, n0_ = ((Hh) & 1) * 2;                        \
        w1r[S][0] = gload16(bb + (size_t)((wn * 4 + n0_    ) * 8 + ks_) * 1024);\
        w1r[S][1] = gload16(bb + (size_t)((wn * 4 + n0_ + 1) * 8 + ks_) * 1024);\
    } while (0)

    // raw f32 LDS loads for k-pair `ks` (no cvt yet)
#define KF_LOAD(ks, FR)                                                          \
    do {                                                                         \
        const int s0_ = (ks) * 8 + lhi * 2;                                      \
        const int x_  = llo & 7;                                                 \
        FR[0] = *(const f32x4*)(Kb + (llo     ) * 1024 + ((s0_    ) ^ x_) * 16); \
        FR[1] = *(const f32x4*)(Kb + (llo     ) * 1024 + ((s0_ + 1) ^ x_) * 16); \
        FR[2] = *(const f32x4*)(Kb + (16 + llo) * 1024 + ((s0_    ) ^ x_) * 16); \
        FR[3] = *(const f32x4*)(Kb + (16 + llo) * 1024 + ((s0_ + 1) ^ x_) * 16); \
    } while (0)

    // cvt staged f32 -> bf16 fragments
#define KF_CVT(FR, K0, K1)                                                         \
    do {                                                                           \
        union KU { unsigned u[4]; bf16x8 v; } c0_, c1_;                            \
        asm("v_cvt_pk_bf16_f32 %0, %1, %2" : "=v"(c0_.u[0]) : "v"(FR[0][0]), "v"(FR[0][1])); \
        asm("v_cvt_pk_bf16_f32 %0, %1, %2" : "=v"(c0_.u[1]) : "v"(FR[0][2]), "v"(FR[0][3])); \
        asm("v_cvt_pk_bf16_f32 %0, %1, %2" : "=v"(c0_.u[2]) : "v"(FR[1][0]), "v"(FR[1][1])); \
        asm("v_cvt_pk_bf16_f32 %0, %1, %2" : "=v"(c0_.u[3]) : "v"(FR[1][2]), "v"(FR[1][3])); \
        asm("v_cvt_pk_bf16_f32 %0, %1, %2" : "=v"(c1_.u[0]) : "v"(FR[2][0]), "v"(FR[2][1])); \
        asm("v_cvt_pk_bf16_f32 %0, %1, %2" : "=v"(c1_.u[1]) : "v"(FR[2][2]), "v"(FR[2][3])); \
        asm("v_cvt_pk_bf16_f32 %0, %1, %2" : "=v"(c1_.u[2]) : "v"(FR[3][0]), "v"(FR[3][1])); \
        asm("v_cvt_pk_bf16_f32 %0, %1, %2" : "=v"(c1_.u[3]) : "v"(FR[3][2]), "v"(FR[3][3])); \
        K0 = c0_.v; K1 = c1_.v;                                                    \
    } while (0)

    ISSUE_HALF(0, 0); ISSUE_HALF(1, 1); ISSUE_HALF(2, 2); ISSUE_HALF(3, 3);
    waitvm(8); SB0();                      // GLD retired, ring (8) in flight
    __builtin_amdgcn_s_barrier();          // buf 0 visible

#pragma unroll 1
    for (int j = 0; j < TILES; ++j) {
        const int m0 = base + j * BM;
        const unsigned char* Kb = &Kbuf[j & 1][0];

        f32x4 acc[4][2];
#pragma unroll
        for (int a = 0; a < 4; ++a)
#pragma unroll
            for (int b = 0; b < 2; ++b) acc[a][b] = (f32x4){0.f, 0.f, 0.f, 0.f};

        bf16x8 kf[2][2];      // [pair parity][mt]
        f32x4  fr[4];         // in-flight raw pair
        // prologue: pair 0 load + cvt
        KF_LOAD(0, fr);
        KF_CVT(fr, kf[0][0], kf[0][1]);

#pragma unroll
        for (int Hh = 0; Hh < 16; ++Hh) {
            const int p   = Hh >> 1;      // pair index (compile-time, unrolled)
            const int cur = p & 1;
            const int nxt = cur ^ 1;
            if ((Hh & 1) == 0 && p < 7)
                KF_LOAD(p + 1, fr);       // issue early; cvt at pair end

            // counted waits: ring half Hh ready; GLD (8) stays in flight Hh>=12
            if (Hh <= 11)            waitvm(6);
            else if (j < TILES - 1)  waitvm(8 + (15 - Hh) * 2);   // 14,12,10,8
            else                     waitvm((15 - Hh) * 2);       // 6,4,2,0
            SB0();

            {
                const int slot = Hh & 3;
                const int nt0  = (Hh & 1) * 2;
                acc[nt0    ][0] = __builtin_amdgcn_mfma_f32_16x16x32_bf16(w1r[slot][0], kf[cur][0], acc[nt0    ][0], 0, 0, 0);
                acc[nt0    ][1] = __builtin_amdgcn_mfma_f32_16x16x32_bf16(w1r[slot][0], kf[cur][1], acc[nt0    ][1], 0, 0, 0);
                acc[nt0 + 1][0] = __builtin_amdgcn_mfma_f32_16x16x32_bf16(w1r[slot][1], kf[cur][0], acc[nt0 + 1][0], 0, 0, 0);
                acc[nt0 + 1][1] = __builtin_amdgcn_mfma_f32_16x16x32_bf16(w1r[slot][1], kf[cur][1], acc[nt0 + 1][1], 0, 0, 0);
            }
            if (Hh < 12) ISSUE_HALF(Hh + 4, Hh & 3);          // refill consumed slot
            if ((Hh & 1) == 1 && p < 7)
                KF_CVT(fr, kf[nxt][0], kf[nxt][1]);           // lgkm lands ~2 phases after issue
            if (Hh == 11 && j < TILES - 1) {                  // stage tile j+1
                unsigned char* nb = &Kbuf[(j + 1) & 1][0];
#pragma unroll
                for (int i = 0; i < 8; ++i) {
                    int r = i * 4 + wave;
                    const float* g = kin + (size_t)(m0 + BM + r) * H + ((lane ^ (r & 7)) << 2);
                    gload_lds16(g, nb + r * 1024);
                }
            }
        }

        // ---- epilogue ----
        __builtin_amdgcn_s_barrier();            // all waves done reading Kb
        float* part = (float*)(&Kbuf[j & 1][0]); // dead buffer reused
        float sm0 = 0.f, sm1 = 0.f;
#pragma unroll
        for (int nt = 0; nt < 4; ++nt)
#pragma unroll
            for (int i = 0; i < 4; ++i) {
                float x0 = acc[nt][0][i] + qv[nt][i];
                float e0 = __expf(2.f * x0);
                sm0 += (1.f - 2.f * __builtin_amdgcn_rcpf(e0 + 1.f)) * vv[nt][i];
                float x1 = acc[nt][1][i] + qv[nt][i];
                float e1 = __expf(2.f * x1);
                sm1 += (1.f - 2.f * __builtin_amdgcn_rcpf(e1 + 1.f)) * vv[nt][i];
            }
        sm0 += __shfl_xor(sm0, 16, 64); sm0 += __shfl_xor(sm0, 32, 64);
        sm1 += __shfl_xor(sm1, 16, 64); sm1 += __shfl_xor(sm1, 32, 64);
        if (lane < 16) {
            part[wn * 32 +  0 + lane] = sm0;
            part[wn * 32 + 16 + lane] = sm1;
        }
        asm volatile("s_waitcnt lgkmcnt(0)" ::: "memory");
        __builtin_amdgcn_s_barrier();
        SB0();
        if (t < BM) {
            float r = part[t] + part[32 + t] + part[64 + t] + part[96 + t];
            gstore(out_scores + m0 + t, r);
        }
        if (j < TILES - 1) {
            ISSUE_HALF(0, 0); ISSUE_HALF(1, 1); ISSUE_HALF(2, 2); ISSUE_HALF(3, 3);
            waitvm(8); SB0();                    // GLD+store retired, ring kept
            __builtin_amdgcn_s_barrier();        // buf j+1 visible
        }
    }
#undef ISSUE_HALF
#undef KF_LOAD
#undef KF_CVT
}

// ---------------- softmax over seq axis, in-place on d_out ----------------
__global__ __launch_bounds__(256) void softmax_kernel(float* __restrict__ out) {
    const int b = blockIdx.x;
    const int t = threadIdx.x;
    float* row = out + b * SEQ;
    float v[8];
#pragma unroll
    for (int j = 0; j < 8; ++j) v[j] = row[t + j * 256];
    float mx = v[0];
#pragma unroll
    for (int j = 1; j < 8; ++j) mx = fmaxf(mx, v[j]);
#pragma unroll
    for (int off = 1; off < 64; off <<= 1) mx = fmaxf(mx, __shfl_xor(mx, off, 64));
    __shared__ float redm[4], reds[4];
    int lane = t & 63, w = t >> 6;
    if (lane == 0) redm[w] = mx;
    __syncthreads();
    mx = fmaxf(fmaxf(redm[0], redm[1]), fmaxf(redm[2], redm[3]));
    float e[8], sum = 0.f;
#pragma unroll
    for (int j = 0; j < 8; ++j) { e[j] = __expf(v[j] - mx); sum += e[j]; }
#pragma unroll
    for (int off = 1; off < 64; off <<= 1) sum += __shfl_xor(sum, off, 64);
    if (lane == 0) reds[w] = sum;
    __syncthreads();
    float inv = 1.0f / (reds[0] + reds[1] + reds[2] + reds[3]);
#pragma unroll
    for (int j = 0; j < 8; ++j) row[t + j * 256] = e[j] * inv;
}

extern "C" void kernel_launch(void* const* d_in, const int* in_sizes, int n_in,
                              void* d_out, int out_size, void* d_ws, size_t ws_size,
                              hipStream_t stream) {
    const float* q  = (const float*)d_in[0];
    const float* k  = (const float*)d_in[1];
    const float* W1 = (const float*)d_in[2];
    const float* b1 = (const float*)d_in[3];
    const float* W2 = (const float*)d_in[4];
    const float* b2 = (const float*)d_in[5];
    const float* V  = (const float*)d_in[6];
    // d_in[7] = bv: softmax-invariant scalar, skipped.
    float* out = (float*)d_out;

    float* qpb     = (float*)d_ws;                                   // 1 KB
    float* partial = (float*)((char*)d_ws + 1024);                   // 16 KB
    unsigned short* Bpack = (unsigned short*)((char*)d_ws + 17408);  // 128 KB

    prep_qpb1<<<16, 256, 0, stream>>>(q, W2, partial);
    prep_misc<<<33, 256, 0, stream>>>(W1, Bpack, partial, b1, b2, qpb);
    fused_main<<<GRID, 256, 0, stream>>>(k, Bpack, qpb, V, out);
    softmax_kernel<<<NBATCH, 256, 0, stream>>>(out);
}